// Round 1
// baseline (254.964 us; speedup 1.0000x reference)
//
#include <hip/hip_runtime.h>

#define N 1024
#define THREADS 256
#define EPT 4  // elements per thread (N / THREADS)

__global__ __launch_bounds__(THREADS) void trifat_kernel(
    const float* __restrict__ x,       // [B, N]
    const float* __restrict__ logits,  // [2, 9, 3]
    const float* __restrict__ diags,   // [2, 10, N, 2]
    const float* __restrict__ subd,    // [2, 10, N, 2]
    const float* __restrict__ supd,    // [2, 10, N, 2]
    const float* __restrict__ bias,    // [N]
    float* __restrict__ out,           // [B, N]
    int B)
{
    __shared__ float2 bufA[N];
    __shared__ float2 bufB[N];

    const int row = blockIdx.x;
    const int tid = threadIdx.x;
    if (row >= B) return;

    // ---- load: real_to_complex ----
    const float* xr = x + (size_t)row * N;
#pragma unroll
    for (int e = 0; e < EPT; ++e) {
        int idx = tid + e * THREADS;
        bufA[idx] = make_float2(xr[idx], 0.0f);
    }
    __syncthreads();

    float2* src = bufA;
    float2* dst = bufB;

    for (int d = 0; d < 2; ++d) {
        // ---- 9 soft block-permutations, s = 4,8,...,1024 ----
        for (int j = 0; j < 9; ++j) {
            const int s = 4 << j;
            const int h = s >> 1;
            const float* lg = logits + (d * 9 + j) * 3;
            const float p0 = 1.0f / (1.0f + expf(-lg[0]));
            const float p1 = 1.0f / (1.0f + expf(-lg[1]));
            const float p2 = 1.0f / (1.0f + expf(-lg[2]));
#pragma unroll
            for (int e = 0; e < EPT; ++e) {
                const int idx = tid + e * THREADS;
                const int base = idx & ~(s - 1);
                const int t = idx & (s - 1);
                const bool lo = (t < h);

                // y(t) = (1-p0)*x[t] + p0*eo(t)
                const int eo_t = lo ? (2 * t) : (2 * (t - h) + 1);
                const float2 xt  = src[idx];
                const float2 xeo = src[base + eo_t];
                float2 yt;
                yt.x = xt.x + p0 * (xeo.x - xt.x);
                yt.y = xt.y + p0 * (xeo.y - xt.y);

                // mirror within half
                const int tm = lo ? (h - 1 - t) : (s + h - 1 - t);
                const float psel = lo ? p1 : p2;
                const int eo_m = (tm < h) ? (2 * tm) : (2 * (tm - h) + 1);
                const float2 xm   = src[base + tm];
                const float2 xmeo = src[base + eo_m];
                float2 ym;
                ym.x = xm.x + p0 * (xmeo.x - xm.x);
                ym.y = xm.y + p0 * (xmeo.y - xm.y);

                float2 o;
                o.x = yt.x + psel * (ym.x - yt.x);
                o.y = yt.y + psel * (ym.y - yt.y);
                dst[idx] = o;
            }
            __syncthreads();
            float2* tmp = src; src = dst; dst = tmp;
        }
        // ---- 10 butterflies, k = 512,256,...,1 ----
        for (int i = 0; i < 10; ++i) {
            const int k = N >> (i + 1);
            const float2* Dg = (const float2*)(diags + (size_t)((d * 10 + i) * N) * 2);
            const float2* Sb = (const float2*)(subd  + (size_t)((d * 10 + i) * N) * 2);
            const float2* Sp = (const float2*)(supd  + (size_t)((d * 10 + i) * N) * 2);
#pragma unroll
            for (int e = 0; e < EPT; ++e) {
                const int idx = tid + e * THREADS;
                const float2 xv = src[idx];
                const float2 dg = Dg[idx];
                float2 o;
                o.x = dg.x * xv.x - dg.y * xv.y;
                o.y = dg.x * xv.y + dg.y * xv.x;
                if (idx >= k) {
                    const float2 xs = src[idx - k];
                    const float2 sb = Sb[idx - k];
                    o.x += sb.x * xs.x - sb.y * xs.y;
                    o.y += sb.x * xs.y + sb.y * xs.x;
                }
                if (idx < N - k) {
                    const float2 xp = src[idx + k];
                    const float2 sp = Sp[idx];
                    o.x += sp.x * xp.x - sp.y * xp.y;
                    o.y += sp.x * xp.y + sp.y * xp.x;
                }
                dst[idx] = o;
            }
            __syncthreads();
            float2* tmp = src; src = dst; dst = tmp;
        }
    }

    // ---- store: real part + bias ----
    float* orow = out + (size_t)row * N;
#pragma unroll
    for (int e = 0; e < EPT; ++e) {
        int idx = tid + e * THREADS;
        orow[idx] = src[idx].x + bias[idx];
    }
}

extern "C" void kernel_launch(void* const* d_in, const int* in_sizes, int n_in,
                              void* d_out, int out_size, void* d_ws, size_t ws_size,
                              hipStream_t stream) {
    const float* x      = (const float*)d_in[0];
    const float* logits = (const float*)d_in[1];
    const float* diags  = (const float*)d_in[2];
    const float* subd   = (const float*)d_in[3];
    const float* supd   = (const float*)d_in[4];
    const float* bias   = (const float*)d_in[5];
    float* out = (float*)d_out;

    const int B = in_sizes[0] / N;  // 4096
    dim3 grid(B), block(THREADS);
    trifat_kernel<<<grid, block, 0, stream>>>(x, logits, diags, subd, supd, bias, out, B);
}

// Round 2
// 225.999 us; speedup vs baseline: 1.1282x; 1.1282x over previous
//
#include <hip/hip_runtime.h>

#define N 1024
#define THREADS 256
#define EPT 4  // elements per thread (N / THREADS)

// ---------------------------------------------------------------------------
// Shared pass pipeline: applies the full 2-depth perm+butterfly chain to the
// complex vector in bufA/bufB (LDS). Returns pointer to the buffer holding
// the final result.
// ---------------------------------------------------------------------------
__device__ __forceinline__ float2* run_pipeline(
    float2* bufA, float2* bufB, int tid,
    const float* __restrict__ logits,
    const float* __restrict__ diags,
    const float* __restrict__ subd,
    const float* __restrict__ supd)
{
    float2* src = bufA;
    float2* dst = bufB;

    for (int d = 0; d < 2; ++d) {
        // ---- 9 soft block-permutations, s = 4,8,...,1024 ----
        for (int j = 0; j < 9; ++j) {
            const int s = 4 << j;
            const int h = s >> 1;
            const float* lg = logits + (d * 9 + j) * 3;
            const float p0 = 1.0f / (1.0f + expf(-lg[0]));
            const float p1 = 1.0f / (1.0f + expf(-lg[1]));
            const float p2 = 1.0f / (1.0f + expf(-lg[2]));
#pragma unroll
            for (int e = 0; e < EPT; ++e) {
                const int idx = tid + e * THREADS;
                const int base = idx & ~(s - 1);
                const int t = idx & (s - 1);
                const bool lo = (t < h);

                const int eo_t = lo ? (2 * t) : (2 * (t - h) + 1);
                const float2 xt  = src[idx];
                const float2 xeo = src[base + eo_t];
                float2 yt;
                yt.x = xt.x + p0 * (xeo.x - xt.x);
                yt.y = xt.y + p0 * (xeo.y - xt.y);

                const int tm = lo ? (h - 1 - t) : (s + h - 1 - t);
                const float psel = lo ? p1 : p2;
                const int eo_m = (tm < h) ? (2 * tm) : (2 * (tm - h) + 1);
                const float2 xm   = src[base + tm];
                const float2 xmeo = src[base + eo_m];
                float2 ym;
                ym.x = xm.x + p0 * (xmeo.x - xm.x);
                ym.y = xm.y + p0 * (xmeo.y - xm.y);

                float2 o;
                o.x = yt.x + psel * (ym.x - yt.x);
                o.y = yt.y + psel * (ym.y - yt.y);
                dst[idx] = o;
            }
            __syncthreads();
            float2* tmp = src; src = dst; dst = tmp;
        }
        // ---- 10 butterflies, k = 512,256,...,1 ----
        for (int i = 0; i < 10; ++i) {
            const int k = N >> (i + 1);
            const float2* Dg = (const float2*)(diags + (size_t)((d * 10 + i) * N) * 2);
            const float2* Sb = (const float2*)(subd  + (size_t)((d * 10 + i) * N) * 2);
            const float2* Sp = (const float2*)(supd  + (size_t)((d * 10 + i) * N) * 2);
#pragma unroll
            for (int e = 0; e < EPT; ++e) {
                const int idx = tid + e * THREADS;
                const float2 xv = src[idx];
                const float2 dg = Dg[idx];
                float2 o;
                o.x = dg.x * xv.x - dg.y * xv.y;
                o.y = dg.x * xv.y + dg.y * xv.x;
                if (idx >= k) {
                    const float2 xs = src[idx - k];
                    const float2 sb = Sb[idx - k];
                    o.x += sb.x * xs.x - sb.y * xs.y;
                    o.y += sb.x * xs.y + sb.y * xs.x;
                }
                if (idx < N - k) {
                    const float2 xp = src[idx + k];
                    const float2 sp = Sp[idx];
                    o.x += sp.x * xp.x - sp.y * xp.y;
                    o.y += sp.x * xp.y + sp.y * xp.x;
                }
                dst[idx] = o;
            }
            __syncthreads();
            float2* tmp = src; src = dst; dst = tmp;
        }
    }
    return src;
}

// ---------------------------------------------------------------------------
// Fallback: direct per-row kernel (round-1, known correct).
// ---------------------------------------------------------------------------
__global__ __launch_bounds__(THREADS) void trifat_kernel(
    const float* __restrict__ x,
    const float* __restrict__ logits,
    const float* __restrict__ diags,
    const float* __restrict__ subd,
    const float* __restrict__ supd,
    const float* __restrict__ bias,
    float* __restrict__ out,
    int B)
{
    __shared__ float2 bufA[N];
    __shared__ float2 bufB[N];

    const int row = blockIdx.x;
    const int tid = threadIdx.x;
    if (row >= B) return;

    const float* xr = x + (size_t)row * N;
#pragma unroll
    for (int e = 0; e < EPT; ++e) {
        int idx = tid + e * THREADS;
        bufA[idx] = make_float2(xr[idx], 0.0f);
    }
    __syncthreads();

    float2* res = run_pipeline(bufA, bufB, tid, logits, diags, subd, supd);

    float* orow = out + (size_t)row * N;
#pragma unroll
    for (int e = 0; e < EPT; ++e) {
        int idx = tid + e * THREADS;
        orow[idx] = res[idx].x + bias[idx];
    }
}

// ---------------------------------------------------------------------------
// Stage 1: W[j][n] = Re(pipeline(e_j))[n]   (row j = image of basis vector j)
// ---------------------------------------------------------------------------
__global__ __launch_bounds__(THREADS) void build_W(
    const float* __restrict__ logits,
    const float* __restrict__ diags,
    const float* __restrict__ subd,
    const float* __restrict__ supd,
    float* __restrict__ W)
{
    __shared__ float2 bufA[N];
    __shared__ float2 bufB[N];

    const int j = blockIdx.x;
    const int tid = threadIdx.x;

#pragma unroll
    for (int e = 0; e < EPT; ++e) {
        int idx = tid + e * THREADS;
        bufA[idx] = make_float2(idx == j ? 1.0f : 0.0f, 0.0f);
    }
    __syncthreads();

    float2* res = run_pipeline(bufA, bufB, tid, logits, diags, subd, supd);

#pragma unroll
    for (int e = 0; e < EPT; ++e) {
        int idx = tid + e * THREADS;
        W[(size_t)j * N + idx] = res[idx].x;
    }
}

// ---------------------------------------------------------------------------
// bf16 split helpers
// ---------------------------------------------------------------------------
__device__ __forceinline__ unsigned short f2bf_rne(float f) {
    unsigned int u = __float_as_uint(f);
    unsigned int r = u + 0x7fffu + ((u >> 16) & 1u);
    return (unsigned short)(r >> 16);
}
__device__ __forceinline__ float bf2f(unsigned short h) {
    return __uint_as_float(((unsigned int)h) << 16);
}

// ---------------------------------------------------------------------------
// Stage 2a: transpose + split W into Bt [1024][3072] bf16:
//   Bt[n][j]      = hi(W[j][n])
//   Bt[n][1024+j] = lo(W[j][n])
//   Bt[n][2048+j] = hi(W[j][n])
// ---------------------------------------------------------------------------
__global__ __launch_bounds__(THREADS) void transpose_split(
    const float* __restrict__ W, unsigned short* __restrict__ Bt)
{
    __shared__ float tile[64][65];
    const int j0 = blockIdx.x * 64;
    const int n0 = blockIdx.y * 64;
    const int t = threadIdx.x;
    const int c = t & 63;
    const int rb = t >> 6;  // 0..3

#pragma unroll
    for (int rr = 0; rr < 16; ++rr) {
        const int r = rr * 4 + rb;
        tile[r][c] = W[(size_t)(j0 + r) * N + n0 + c];
    }
    __syncthreads();
#pragma unroll
    for (int rr = 0; rr < 16; ++rr) {
        const int r = rr * 4 + rb;       // output row n0+r
        const float v = tile[c][r];      // = W[j0+c][n0+r]
        const unsigned short hi = f2bf_rne(v);
        const unsigned short lo = f2bf_rne(v - bf2f(hi));
        unsigned short* row = Bt + (size_t)(n0 + r) * 3072;
        row[j0 + c]        = hi;
        row[1024 + j0 + c] = lo;
        row[2048 + j0 + c] = hi;
    }
}

// ---------------------------------------------------------------------------
// Stage 2b: split x into A2 [B][2048] bf16: A2[b][k]=hi, A2[b][1024+k]=lo
// ---------------------------------------------------------------------------
__global__ __launch_bounds__(THREADS) void conv_x(
    const float* __restrict__ x, unsigned short* __restrict__ A2)
{
    const int idx = blockIdx.x * THREADS + threadIdx.x;
    const float v = x[idx];
    const unsigned short hi = f2bf_rne(v);
    const unsigned short lo = f2bf_rne(v - bf2f(hi));
    const int b = idx >> 10, k = idx & 1023;
    A2[(size_t)b * 2048 + k]        = hi;
    A2[(size_t)b * 2048 + 1024 + k] = lo;
}

// ---------------------------------------------------------------------------
// Stage 3: out[b][n] = sum_k' A'[b][k'] * B'[k'][n] + bias[n], K'=3072
//   logical k' in [0,1024): xh*Wh ; [1024,2048): xh*Wl ; [2048,3072): xl*Wh
//   physical A2 k-offset: kt<16 ? k0 : k0-1024
// 64x64 tile, BK=64, 256 threads (4 waves), each wave a 32x32 quadrant.
// ---------------------------------------------------------------------------
typedef __attribute__((ext_vector_type(8))) __bf16 bf16x8;
typedef __attribute__((ext_vector_type(4))) float f32x4;

#define LDK 72  // padded LDS row length (bf16 elems): breaks 16-way conflicts

__global__ __launch_bounds__(THREADS) void gemm_split(
    const unsigned short* __restrict__ A2,  // [B][2048]
    const unsigned short* __restrict__ Bt,  // [1024][3072]
    const float* __restrict__ bias,
    float* __restrict__ out)
{
    __shared__ __align__(16) unsigned short As[64 * LDK];
    __shared__ __align__(16) unsigned short Bs[64 * LDK];

    const int m0 = blockIdx.x * 64;
    const int n0 = blockIdx.y * 64;
    const int tid = threadIdx.x;
    const int wave = tid >> 6, lane = tid & 63;
    const int moff = (wave >> 1) * 32, noff = (wave & 1) * 32;
    const int lrow = lane & 15, q = lane >> 4;

    f32x4 acc[2][2] = {};

    const int srow = tid >> 3;        // 0..31
    const int scol = (tid & 7) * 8;   // 0,8,...,56

    for (int kt = 0; kt < 48; ++kt) {
        const int k0 = kt * 64;
        const int ka = (kt < 16) ? k0 : (k0 - 1024);
        __syncthreads();
#pragma unroll
        for (int rr = 0; rr < 2; ++rr) {
            const int r = srow + rr * 32;
            const uint4 av = *(const uint4*)(A2 + (size_t)(m0 + r) * 2048 + ka + scol);
            *(uint4*)(As + r * LDK + scol) = av;
            const uint4 bv = *(const uint4*)(Bt + (size_t)(n0 + r) * 3072 + k0 + scol);
            *(uint4*)(Bs + r * LDK + scol) = bv;
        }
        __syncthreads();
#pragma unroll
        for (int kk = 0; kk < 64; kk += 32) {
            const bf16x8 a0 = *(const bf16x8*)(As + (moff + lrow) * LDK + kk + q * 8);
            const bf16x8 a1 = *(const bf16x8*)(As + (moff + 16 + lrow) * LDK + kk + q * 8);
            const bf16x8 b0 = *(const bf16x8*)(Bs + (noff + lrow) * LDK + kk + q * 8);
            const bf16x8 b1 = *(const bf16x8*)(Bs + (noff + 16 + lrow) * LDK + kk + q * 8);
            acc[0][0] = __builtin_amdgcn_mfma_f32_16x16x32_bf16(a0, b0, acc[0][0], 0, 0, 0);
            acc[0][1] = __builtin_amdgcn_mfma_f32_16x16x32_bf16(a0, b1, acc[0][1], 0, 0, 0);
            acc[1][0] = __builtin_amdgcn_mfma_f32_16x16x32_bf16(a1, b0, acc[1][0], 0, 0, 0);
            acc[1][1] = __builtin_amdgcn_mfma_f32_16x16x32_bf16(a1, b1, acc[1][1], 0, 0, 0);
        }
    }

#pragma unroll
    for (int mi = 0; mi < 2; ++mi)
#pragma unroll
        for (int ni = 0; ni < 2; ++ni)
#pragma unroll
            for (int r = 0; r < 4; ++r) {
                const int row = m0 + moff + mi * 16 + q * 4 + r;
                const int col = n0 + noff + ni * 16 + lrow;
                out[(size_t)row * N + col] = acc[mi][ni][r] + bias[col];
            }
}

// ---------------------------------------------------------------------------
extern "C" void kernel_launch(void* const* d_in, const int* in_sizes, int n_in,
                              void* d_out, int out_size, void* d_ws, size_t ws_size,
                              hipStream_t stream) {
    const float* x      = (const float*)d_in[0];
    const float* logits = (const float*)d_in[1];
    const float* diags  = (const float*)d_in[2];
    const float* subd   = (const float*)d_in[3];
    const float* supd   = (const float*)d_in[4];
    const float* bias   = (const float*)d_in[5];
    float* out = (float*)d_out;

    const int B = in_sizes[0] / N;  // 4096

    const size_t off_W  = 0;
    const size_t off_Bt = 4u * 1024 * 1024;                 // W: 1024*1024*4 B
    const size_t off_A2 = off_Bt + 6u * 1024 * 1024;        // Bt: 1024*3072*2 B
    const size_t need   = off_A2 + (size_t)B * 2048 * 2;    // A2: B*2048*2 B

    if (ws_size >= need && (B % 64) == 0) {
        float* W           = (float*)((char*)d_ws + off_W);
        unsigned short* Bt = (unsigned short*)((char*)d_ws + off_Bt);
        unsigned short* A2 = (unsigned short*)((char*)d_ws + off_A2);

        build_W<<<dim3(N), dim3(THREADS), 0, stream>>>(logits, diags, subd, supd, W);
        transpose_split<<<dim3(16, 16), dim3(THREADS), 0, stream>>>(W, Bt);
        conv_x<<<dim3(B * N / THREADS), dim3(THREADS), 0, stream>>>(x, A2);
        gemm_split<<<dim3(B / 64, 16), dim3(THREADS), 0, stream>>>(A2, Bt, bias, out);
    } else {
        trifat_kernel<<<dim3(B), dim3(THREADS), 0, stream>>>(
            x, logits, diags, subd, supd, bias, out, B);
    }
}

// Round 3
// 206.400 us; speedup vs baseline: 1.2353x; 1.0950x over previous
//
#include <hip/hip_runtime.h>

#define N 1024
#define THREADS 256
#define EPT 4  // elements per thread (N / THREADS)

// ---------------------------------------------------------------------------
// Shared pass pipeline (unchanged, known correct).
// ---------------------------------------------------------------------------
__device__ __forceinline__ float2* run_pipeline(
    float2* bufA, float2* bufB, int tid,
    const float* __restrict__ logits,
    const float* __restrict__ diags,
    const float* __restrict__ subd,
    const float* __restrict__ supd)
{
    float2* src = bufA;
    float2* dst = bufB;

    for (int d = 0; d < 2; ++d) {
        for (int j = 0; j < 9; ++j) {
            const int s = 4 << j;
            const int h = s >> 1;
            const float* lg = logits + (d * 9 + j) * 3;
            const float p0 = 1.0f / (1.0f + expf(-lg[0]));
            const float p1 = 1.0f / (1.0f + expf(-lg[1]));
            const float p2 = 1.0f / (1.0f + expf(-lg[2]));
#pragma unroll
            for (int e = 0; e < EPT; ++e) {
                const int idx = tid + e * THREADS;
                const int base = idx & ~(s - 1);
                const int t = idx & (s - 1);
                const bool lo = (t < h);

                const int eo_t = lo ? (2 * t) : (2 * (t - h) + 1);
                const float2 xt  = src[idx];
                const float2 xeo = src[base + eo_t];
                float2 yt;
                yt.x = xt.x + p0 * (xeo.x - xt.x);
                yt.y = xt.y + p0 * (xeo.y - xt.y);

                const int tm = lo ? (h - 1 - t) : (s + h - 1 - t);
                const float psel = lo ? p1 : p2;
                const int eo_m = (tm < h) ? (2 * tm) : (2 * (tm - h) + 1);
                const float2 xm   = src[base + tm];
                const float2 xmeo = src[base + eo_m];
                float2 ym;
                ym.x = xm.x + p0 * (xmeo.x - xm.x);
                ym.y = xm.y + p0 * (xmeo.y - xm.y);

                float2 o;
                o.x = yt.x + psel * (ym.x - yt.x);
                o.y = yt.y + psel * (ym.y - yt.y);
                dst[idx] = o;
            }
            __syncthreads();
            float2* tmp = src; src = dst; dst = tmp;
        }
        for (int i = 0; i < 10; ++i) {
            const int k = N >> (i + 1);
            const float2* Dg = (const float2*)(diags + (size_t)((d * 10 + i) * N) * 2);
            const float2* Sb = (const float2*)(subd  + (size_t)((d * 10 + i) * N) * 2);
            const float2* Sp = (const float2*)(supd  + (size_t)((d * 10 + i) * N) * 2);
#pragma unroll
            for (int e = 0; e < EPT; ++e) {
                const int idx = tid + e * THREADS;
                const float2 xv = src[idx];
                const float2 dg = Dg[idx];
                float2 o;
                o.x = dg.x * xv.x - dg.y * xv.y;
                o.y = dg.x * xv.y + dg.y * xv.x;
                if (idx >= k) {
                    const float2 xs = src[idx - k];
                    const float2 sb = Sb[idx - k];
                    o.x += sb.x * xs.x - sb.y * xs.y;
                    o.y += sb.x * xs.y + sb.y * xs.x;
                }
                if (idx < N - k) {
                    const float2 xp = src[idx + k];
                    const float2 sp = Sp[idx];
                    o.x += sp.x * xp.x - sp.y * xp.y;
                    o.y += sp.x * xp.y + sp.y * xp.x;
                }
                dst[idx] = o;
            }
            __syncthreads();
            float2* tmp = src; src = dst; dst = tmp;
        }
    }
    return src;
}

// ---------------------------------------------------------------------------
// Fallback: direct per-row kernel (round-1, known correct).
// ---------------------------------------------------------------------------
__global__ __launch_bounds__(THREADS) void trifat_kernel(
    const float* __restrict__ x,
    const float* __restrict__ logits,
    const float* __restrict__ diags,
    const float* __restrict__ subd,
    const float* __restrict__ supd,
    const float* __restrict__ bias,
    float* __restrict__ out,
    int B)
{
    __shared__ float2 bufA[N];
    __shared__ float2 bufB[N];

    const int row = blockIdx.x;
    const int tid = threadIdx.x;
    if (row >= B) return;

    const float* xr = x + (size_t)row * N;
#pragma unroll
    for (int e = 0; e < EPT; ++e) {
        int idx = tid + e * THREADS;
        bufA[idx] = make_float2(xr[idx], 0.0f);
    }
    __syncthreads();

    float2* res = run_pipeline(bufA, bufB, tid, logits, diags, subd, supd);

    float* orow = out + (size_t)row * N;
#pragma unroll
    for (int e = 0; e < EPT; ++e) {
        int idx = tid + e * THREADS;
        orow[idx] = res[idx].x + bias[idx];
    }
}

// ---------------------------------------------------------------------------
// Stage 1: W[j][n] = Re(pipeline(e_j))[n]
// ---------------------------------------------------------------------------
__global__ __launch_bounds__(THREADS) void build_W(
    const float* __restrict__ logits,
    const float* __restrict__ diags,
    const float* __restrict__ subd,
    const float* __restrict__ supd,
    float* __restrict__ W)
{
    __shared__ float2 bufA[N];
    __shared__ float2 bufB[N];

    const int j = blockIdx.x;
    const int tid = threadIdx.x;

#pragma unroll
    for (int e = 0; e < EPT; ++e) {
        int idx = tid + e * THREADS;
        bufA[idx] = make_float2(idx == j ? 1.0f : 0.0f, 0.0f);
    }
    __syncthreads();

    float2* res = run_pipeline(bufA, bufB, tid, logits, diags, subd, supd);

#pragma unroll
    for (int e = 0; e < EPT; ++e) {
        int idx = tid + e * THREADS;
        W[(size_t)j * N + idx] = res[idx].x;
    }
}

// ---------------------------------------------------------------------------
// bf16 split helpers
// ---------------------------------------------------------------------------
__device__ __forceinline__ unsigned short f2bf_rne(float f) {
    unsigned int u = __float_as_uint(f);
    unsigned int r = u + 0x7fffu + ((u >> 16) & 1u);
    return (unsigned short)(r >> 16);
}
__device__ __forceinline__ float bf2f(unsigned short h) {
    return __uint_as_float(((unsigned int)h) << 16);
}

// ---------------------------------------------------------------------------
// Stage 2a: transpose + split W into Bt [1024][2048] bf16 = [Wh | Wl]:
//   Bt[n][j]      = hi(W[j][n])
//   Bt[n][1024+j] = lo(W[j][n])
// ---------------------------------------------------------------------------
__global__ __launch_bounds__(THREADS) void transpose_split(
    const float* __restrict__ W, unsigned short* __restrict__ Bt)
{
    __shared__ float tile[64][65];
    const int j0 = blockIdx.x * 64;
    const int n0 = blockIdx.y * 64;
    const int t = threadIdx.x;
    const int c = t & 63;
    const int rb = t >> 6;  // 0..3

#pragma unroll
    for (int rr = 0; rr < 16; ++rr) {
        const int r = rr * 4 + rb;
        tile[r][c] = W[(size_t)(j0 + r) * N + n0 + c];
    }
    __syncthreads();
#pragma unroll
    for (int rr = 0; rr < 16; ++rr) {
        const int r = rr * 4 + rb;       // output row n0+r
        const float v = tile[c][r];      // = W[j0+c][n0+r]
        const unsigned short hi = f2bf_rne(v);
        const unsigned short lo = f2bf_rne(v - bf2f(hi));
        unsigned short* row = Bt + (size_t)(n0 + r) * 2048;
        row[j0 + c]        = hi;
        row[1024 + j0 + c] = lo;
    }
}

// ---------------------------------------------------------------------------
// Stage 2b: split x into A2 [B][2048] bf16: A2[b][k]=hi, A2[b][1024+k]=lo
// ---------------------------------------------------------------------------
__global__ __launch_bounds__(THREADS) void conv_x(
    const float* __restrict__ x, unsigned short* __restrict__ A2)
{
    const int idx = blockIdx.x * THREADS + threadIdx.x;
    const float v = x[idx];
    const unsigned short hi = f2bf_rne(v);
    const unsigned short lo = f2bf_rne(v - bf2f(hi));
    const int b = idx >> 10, k = idx & 1023;
    A2[(size_t)b * 2048 + k]        = hi;
    A2[(size_t)b * 2048 + 1024 + k] = lo;
}

// ---------------------------------------------------------------------------
// Stage 3: m97-style 128x128 GEMM, BK=64, K' = 3072 logical:
//   kt  0..15 : xh * Wh      kt 16..31 : xh * Wl      kt 32..47 : xl * Wh
// A2 [B][2048]=[xh|xl], Bt [1024][2048]=[Wh|Wl].
// 256 threads = 4 waves (2x2), wave tile 64x64 = 4x4 MFMA 16x16x32 frags.
// global_load_lds width-16 staging into XOR-swizzled LDS (group ^= row&7):
// unpadded layout (DMA requirement) but only 2-way bank aliasing on
// ds_read_b128 (free per m136).
// ---------------------------------------------------------------------------
typedef __attribute__((ext_vector_type(8))) __bf16 bf16x8;
typedef __attribute__((ext_vector_type(4))) float f32x4;

#define GLB(p) ((const __attribute__((address_space(1))) void*)(p))
#define LDS(p) ((__attribute__((address_space(3))) void*)(p))

__global__ __launch_bounds__(THREADS) void gemm_split(
    const unsigned short* __restrict__ A2,  // [B][2048]
    const unsigned short* __restrict__ Bt,  // [1024][2048]
    const float* __restrict__ bias,
    float* __restrict__ out)
{
    __shared__ __align__(16) unsigned short As[128 * 64];
    __shared__ __align__(16) unsigned short Bs[128 * 64];

    const int m0 = blockIdx.x * 128;
    const int n0 = blockIdx.y * 128;
    const int tid = threadIdx.x;
    const int wave = tid >> 6, lane = tid & 63;
    const int wm = (wave >> 1) * 64, wn = (wave & 1) * 64;
    const int lrow = lane & 15, q = lane >> 4;
    const int r7 = lrow & 7;

    f32x4 acc[4][4] = {};

    for (int kt = 0; kt < 48; ++kt) {
        const int kb16 = (kt & 15) * 64;
        const int ka = kb16 + ((kt >= 32) ? 1024 : 0);               // xh,xh,xl
        const int kb = kb16 + ((kt >= 16 && kt < 32) ? 1024 : 0);    // Wh,Wl,Wh

        __syncthreads();  // previous tile fully consumed
        const unsigned short* gA = A2 + (size_t)m0 * 2048 + ka;
        const unsigned short* gB = Bt + (size_t)n0 * 2048 + kb;
#pragma unroll
        for (int r = 0; r < 4; ++r) {
            const int s = r * 256 + tid;       // 16-byte slot id, wave-contiguous
            const int row = s >> 3;
            const int gl = (s & 7) ^ (row & 7);  // logical k-group for this slot
            __builtin_amdgcn_global_load_lds(GLB(gA + (size_t)row * 2048 + gl * 8),
                                             LDS(As + s * 8), 16, 0, 0);
            __builtin_amdgcn_global_load_lds(GLB(gB + (size_t)row * 2048 + gl * 8),
                                             LDS(Bs + s * 8), 16, 0, 0);
        }
        __syncthreads();  // vmcnt drained -> tile ready

#pragma unroll
        for (int kk = 0; kk < 64; kk += 32) {
            const int pg = ((kk >> 3) + q) ^ r7;   // physical (swizzled) group
            bf16x8 a[4], b[4];
#pragma unroll
            for (int mi = 0; mi < 4; ++mi)
                a[mi] = *(const bf16x8*)(As + (wm + mi * 16 + lrow) * 64 + pg * 8);
#pragma unroll
            for (int ni = 0; ni < 4; ++ni)
                b[ni] = *(const bf16x8*)(Bs + (wn + ni * 16 + lrow) * 64 + pg * 8);
#pragma unroll
            for (int mi = 0; mi < 4; ++mi)
#pragma unroll
                for (int ni = 0; ni < 4; ++ni)
                    acc[mi][ni] = __builtin_amdgcn_mfma_f32_16x16x32_bf16(
                        a[mi], b[ni], acc[mi][ni], 0, 0, 0);
        }
    }

    // epilogue: C/D layout col=lane&15, row=q*4+reg
#pragma unroll
    for (int ni = 0; ni < 4; ++ni) {
        const int col = n0 + wn + ni * 16 + lrow;
        const float bv = bias[col];
#pragma unroll
        for (int mi = 0; mi < 4; ++mi)
#pragma unroll
            for (int r = 0; r < 4; ++r) {
                const int row = m0 + wm + mi * 16 + q * 4 + r;
                out[(size_t)row * N + col] = acc[mi][ni][r] + bv;
            }
    }
}

// ---------------------------------------------------------------------------
extern "C" void kernel_launch(void* const* d_in, const int* in_sizes, int n_in,
                              void* d_out, int out_size, void* d_ws, size_t ws_size,
                              hipStream_t stream) {
    const float* x      = (const float*)d_in[0];
    const float* logits = (const float*)d_in[1];
    const float* diags  = (const float*)d_in[2];
    const float* subd   = (const float*)d_in[3];
    const float* supd   = (const float*)d_in[4];
    const float* bias   = (const float*)d_in[5];
    float* out = (float*)d_out;

    const int B = in_sizes[0] / N;  // 4096

    const size_t off_W  = 0;
    const size_t off_Bt = 4u * 1024 * 1024;                 // W:  1024*1024*4 B
    const size_t off_A2 = off_Bt + 4u * 1024 * 1024;        // Bt: 1024*2048*2 B
    const size_t need   = off_A2 + (size_t)B * 2048 * 2;    // A2: B*2048*2 B

    if (ws_size >= need && (B % 128) == 0) {
        float* W           = (float*)((char*)d_ws + off_W);
        unsigned short* Bt = (unsigned short*)((char*)d_ws + off_Bt);
        unsigned short* A2 = (unsigned short*)((char*)d_ws + off_A2);

        build_W<<<dim3(N), dim3(THREADS), 0, stream>>>(logits, diags, subd, supd, W);
        transpose_split<<<dim3(16, 16), dim3(THREADS), 0, stream>>>(W, Bt);
        conv_x<<<dim3(B * N / THREADS), dim3(THREADS), 0, stream>>>(x, A2);
        gemm_split<<<dim3(B / 128, 8), dim3(THREADS), 0, stream>>>(A2, Bt, bias, out);
    } else {
        trifat_kernel<<<dim3(B), dim3(THREADS), 0, stream>>>(
            x, logits, diags, subd, supd, bias, out, B);
    }
}

// Round 4
// 200.227 us; speedup vs baseline: 1.2734x; 1.0308x over previous
//
#include <hip/hip_runtime.h>

#define N 1024
#define THREADS 256
#define EPT 4  // elements per thread per vector (N / THREADS)

// ---------------------------------------------------------------------------
// Shared pass pipeline (fallback path only).
// ---------------------------------------------------------------------------
__device__ __forceinline__ float2* run_pipeline(
    float2* bufA, float2* bufB, int tid,
    const float* __restrict__ logits,
    const float* __restrict__ diags,
    const float* __restrict__ subd,
    const float* __restrict__ supd)
{
    float2* src = bufA;
    float2* dst = bufB;

    for (int d = 0; d < 2; ++d) {
        for (int j = 0; j < 9; ++j) {
            const int s = 4 << j;
            const int h = s >> 1;
            const float* lg = logits + (d * 9 + j) * 3;
            const float p0 = 1.0f / (1.0f + expf(-lg[0]));
            const float p1 = 1.0f / (1.0f + expf(-lg[1]));
            const float p2 = 1.0f / (1.0f + expf(-lg[2]));
#pragma unroll
            for (int e = 0; e < EPT; ++e) {
                const int idx = tid + e * THREADS;
                const int base = idx & ~(s - 1);
                const int t = idx & (s - 1);
                const bool lo = (t < h);

                const int eo_t = lo ? (2 * t) : (2 * (t - h) + 1);
                const float2 xt  = src[idx];
                const float2 xeo = src[base + eo_t];
                float2 yt;
                yt.x = xt.x + p0 * (xeo.x - xt.x);
                yt.y = xt.y + p0 * (xeo.y - xt.y);

                const int tm = lo ? (h - 1 - t) : (s + h - 1 - t);
                const float psel = lo ? p1 : p2;
                const int eo_m = (tm < h) ? (2 * tm) : (2 * (tm - h) + 1);
                const float2 xm   = src[base + tm];
                const float2 xmeo = src[base + eo_m];
                float2 ym;
                ym.x = xm.x + p0 * (xmeo.x - xm.x);
                ym.y = xm.y + p0 * (xmeo.y - xm.y);

                float2 o;
                o.x = yt.x + psel * (ym.x - yt.x);
                o.y = yt.y + psel * (ym.y - yt.y);
                dst[idx] = o;
            }
            __syncthreads();
            float2* tmp = src; src = dst; dst = tmp;
        }
        for (int i = 0; i < 10; ++i) {
            const int k = N >> (i + 1);
            const float2* Dg = (const float2*)(diags + (size_t)((d * 10 + i) * N) * 2);
            const float2* Sb = (const float2*)(subd  + (size_t)((d * 10 + i) * N) * 2);
            const float2* Sp = (const float2*)(supd  + (size_t)((d * 10 + i) * N) * 2);
#pragma unroll
            for (int e = 0; e < EPT; ++e) {
                const int idx = tid + e * THREADS;
                const float2 xv = src[idx];
                const float2 dg = Dg[idx];
                float2 o;
                o.x = dg.x * xv.x - dg.y * xv.y;
                o.y = dg.x * xv.y + dg.y * xv.x;
                if (idx >= k) {
                    const float2 xs = src[idx - k];
                    const float2 sb = Sb[idx - k];
                    o.x += sb.x * xs.x - sb.y * xs.y;
                    o.y += sb.x * xs.y + sb.y * xs.x;
                }
                if (idx < N - k) {
                    const float2 xp = src[idx + k];
                    const float2 sp = Sp[idx];
                    o.x += sp.x * xp.x - sp.y * xp.y;
                    o.y += sp.x * xp.y + sp.y * xp.x;
                }
                dst[idx] = o;
            }
            __syncthreads();
            float2* tmp = src; src = dst; dst = tmp;
        }
    }
    return src;
}

// ---------------------------------------------------------------------------
// Fallback: direct per-row kernel (round-1, known correct).
// ---------------------------------------------------------------------------
__global__ __launch_bounds__(THREADS) void trifat_kernel(
    const float* __restrict__ x,
    const float* __restrict__ logits,
    const float* __restrict__ diags,
    const float* __restrict__ subd,
    const float* __restrict__ supd,
    const float* __restrict__ bias,
    float* __restrict__ out,
    int B)
{
    __shared__ float2 bufA[N];
    __shared__ float2 bufB[N];

    const int row = blockIdx.x;
    const int tid = threadIdx.x;
    if (row >= B) return;

    const float* xr = x + (size_t)row * N;
#pragma unroll
    for (int e = 0; e < EPT; ++e) {
        int idx = tid + e * THREADS;
        bufA[idx] = make_float2(xr[idx], 0.0f);
    }
    __syncthreads();

    float2* res = run_pipeline(bufA, bufB, tid, logits, diags, subd, supd);

    float* orow = out + (size_t)row * N;
#pragma unroll
    for (int e = 0; e < EPT; ++e) {
        int idx = tid + e * THREADS;
        orow[idx] = res[idx].x + bias[idx];
    }
}

// ---------------------------------------------------------------------------
// Stage 1: W[j][n] = Re(pipeline(e_j))[n].
// 2 basis vectors per block (grid = 512 -> 2 blocks/CU), coefficients and
// barriers amortized across both vectors; perm passes use the mirror-pair
// identity (out[t] and out[mirror(t)] share sources {y_t, y_m}).
// ---------------------------------------------------------------------------
__global__ __launch_bounds__(THREADS) void build_W(
    const float* __restrict__ logits,
    const float* __restrict__ diags,
    const float* __restrict__ subd,
    const float* __restrict__ supd,
    float* __restrict__ W)
{
    __shared__ float2 buf[2][2][N];  // [buffer][vector][pos], 32 KB

    const int j0 = blockIdx.x * 2;
    const int tid = threadIdx.x;

#pragma unroll
    for (int v = 0; v < 2; ++v)
#pragma unroll
        for (int e = 0; e < EPT; ++e) {
            const int idx = tid + e * THREADS;
            buf[0][v][idx] = make_float2(idx == (j0 + v) ? 1.0f : 0.0f, 0.0f);
        }
    __syncthreads();

    int sb = 0;
    for (int d = 0; d < 2; ++d) {
        // ---- 9 perm passes, mirror-pair formulation ----
        for (int j = 0; j < 9; ++j) {
            const int s = 4 << j;
            const int h = s >> 1;
            const int hh = s >> 2;  // pairs per half
            const float* lg = logits + (d * 9 + j) * 3;
            const float p0 = 1.0f / (1.0f + expf(-lg[0]));
            const float p1 = 1.0f / (1.0f + expf(-lg[1]));
            const float p2 = 1.0f / (1.0f + expf(-lg[2]));
#pragma unroll
            for (int e = 0; e < 4; ++e) {
                const int tau = tid + e * THREADS;     // 1024 pair-tasks
                const int v = tau >> 9;
                const int pid = tau & 511;             // pair id within vector
                const int w = pid & ((s >> 1) - 1);    // pair within s-block
                const int base = (pid >> (j + 1)) << (j + 2);

                int t, tm;
                float psel;
                if (w < hh) { t = w;          tm = h - 1 - w;  psel = p1; }
                else        { const int u = w - hh; t = h + u; tm = s - 1 - u; psel = p2; }

                const int eot = (t  < h) ? (2 * t)  : (2 * (t  - h) + 1);
                const int eom = (tm < h) ? (2 * tm) : (2 * (tm - h) + 1);

                const float2* src = buf[sb][v];
                float2* dst = buf[sb ^ 1][v];

                const float2 xt = src[base + t],  xet = src[base + eot];
                const float2 xm = src[base + tm], xem = src[base + eom];
                float2 yt, ym;
                yt.x = xt.x + p0 * (xet.x - xt.x);
                yt.y = xt.y + p0 * (xet.y - xt.y);
                ym.x = xm.x + p0 * (xem.x - xm.x);
                ym.y = xm.y + p0 * (xem.y - xm.y);

                float2 ot, om;
                ot.x = yt.x + psel * (ym.x - yt.x);
                ot.y = yt.y + psel * (ym.y - yt.y);
                om.x = ym.x + psel * (yt.x - ym.x);
                om.y = ym.y + psel * (yt.y - ym.y);
                dst[base + t]  = ot;
                dst[base + tm] = om;
            }
            __syncthreads();
            sb ^= 1;
        }
        // ---- 10 butterfly passes, coefficients shared across both vectors ----
        for (int i = 0; i < 10; ++i) {
            const int k = N >> (i + 1);
            const float2* Dg = (const float2*)(diags + (size_t)((d * 10 + i) * N) * 2);
            const float2* Sbc = (const float2*)(subd + (size_t)((d * 10 + i) * N) * 2);
            const float2* Spc = (const float2*)(supd + (size_t)((d * 10 + i) * N) * 2);
#pragma unroll
            for (int e = 0; e < EPT; ++e) {
                const int idx = tid + e * THREADS;
                const float2 dg = Dg[idx];
                float2 sbv = make_float2(0.f, 0.f), spv = make_float2(0.f, 0.f);
                if (idx >= k)     sbv = Sbc[idx - k];
                if (idx < N - k)  spv = Spc[idx];
#pragma unroll
                for (int v = 0; v < 2; ++v) {
                    const float2* src = buf[sb][v];
                    const float2 xv = src[idx];
                    float2 o;
                    o.x = dg.x * xv.x - dg.y * xv.y;
                    o.y = dg.x * xv.y + dg.y * xv.x;
                    if (idx >= k) {
                        const float2 xs = src[idx - k];
                        o.x += sbv.x * xs.x - sbv.y * xs.y;
                        o.y += sbv.x * xs.y + sbv.y * xs.x;
                    }
                    if (idx < N - k) {
                        const float2 xp = src[idx + k];
                        o.x += spv.x * xp.x - spv.y * xp.y;
                        o.y += spv.x * xp.y + spv.y * xp.x;
                    }
                    buf[sb ^ 1][v][idx] = o;
                }
            }
            __syncthreads();
            sb ^= 1;
        }
    }

#pragma unroll
    for (int v = 0; v < 2; ++v)
#pragma unroll
        for (int e = 0; e < EPT; ++e) {
            const int idx = tid + e * THREADS;
            W[(size_t)(j0 + v) * N + idx] = buf[sb][v][idx].x;
        }
}

// ---------------------------------------------------------------------------
// bf16 split helpers
// ---------------------------------------------------------------------------
__device__ __forceinline__ unsigned short f2bf_rne(float f) {
    unsigned int u = __float_as_uint(f);
    unsigned int r = u + 0x7fffu + ((u >> 16) & 1u);
    return (unsigned short)(r >> 16);
}
__device__ __forceinline__ float bf2f(unsigned short h) {
    return __uint_as_float(((unsigned int)h) << 16);
}

// ---------------------------------------------------------------------------
// Stage 2a: transpose + split W into Bt [1024][2048] bf16 = [Wh | Wl]
// ---------------------------------------------------------------------------
__global__ __launch_bounds__(THREADS) void transpose_split(
    const float* __restrict__ W, unsigned short* __restrict__ Bt)
{
    __shared__ float tile[64][65];
    const int j0 = blockIdx.x * 64;
    const int n0 = blockIdx.y * 64;
    const int t = threadIdx.x;
    const int c = t & 63;
    const int rb = t >> 6;  // 0..3

#pragma unroll
    for (int rr = 0; rr < 16; ++rr) {
        const int r = rr * 4 + rb;
        tile[r][c] = W[(size_t)(j0 + r) * N + n0 + c];
    }
    __syncthreads();
#pragma unroll
    for (int rr = 0; rr < 16; ++rr) {
        const int r = rr * 4 + rb;       // output row n0+r
        const float v = tile[c][r];      // = W[j0+c][n0+r]
        const unsigned short hi = f2bf_rne(v);
        const unsigned short lo = f2bf_rne(v - bf2f(hi));
        unsigned short* row = Bt + (size_t)(n0 + r) * 2048;
        row[j0 + c]        = hi;
        row[1024 + j0 + c] = lo;
    }
}

// ---------------------------------------------------------------------------
// Stage 2b: split x into A2 [B][2048] bf16: [xh | xl]
// ---------------------------------------------------------------------------
__global__ __launch_bounds__(THREADS) void conv_x(
    const float* __restrict__ x, unsigned short* __restrict__ A2)
{
    const int idx = blockIdx.x * THREADS + threadIdx.x;
    const float v = x[idx];
    const unsigned short hi = f2bf_rne(v);
    const unsigned short lo = f2bf_rne(v - bf2f(hi));
    const int b = idx >> 10, k = idx & 1023;
    A2[(size_t)b * 2048 + k]        = hi;
    A2[(size_t)b * 2048 + 1024 + k] = lo;
}

// ---------------------------------------------------------------------------
// Stage 3: 128x128 GEMM, BK=64, K'=3072 logical, explicit LDS double-buffer:
// prefetch tile kt+1 via global_load_lds BEFORE computing tile kt, single
// barrier per iter (its vmcnt(0) drain overlaps with the MFMA phase).
// Grid = 256 blocks = 1 block/CU, so intra-block overlap is the only overlap.
// ---------------------------------------------------------------------------
typedef __attribute__((ext_vector_type(8))) __bf16 bf16x8;
typedef __attribute__((ext_vector_type(4))) float f32x4;

#define GLB(p) ((const __attribute__((address_space(1))) void*)(p))
#define LDS(p) ((__attribute__((address_space(3))) void*)(p))

__global__ __launch_bounds__(THREADS) void gemm_split(
    const unsigned short* __restrict__ A2,  // [B][2048] = [xh|xl]
    const unsigned short* __restrict__ Bt,  // [1024][2048] = [Wh|Wl]
    const float* __restrict__ bias,
    float* __restrict__ out)
{
    __shared__ __align__(16) unsigned short As[2][128 * 64];
    __shared__ __align__(16) unsigned short Bs[2][128 * 64];

    const int m0 = blockIdx.x * 128;
    const int n0 = blockIdx.y * 128;
    const int tid = threadIdx.x;
    const int wave = tid >> 6, lane = tid & 63;
    const int wm = (wave >> 1) * 64, wn = (wave & 1) * 64;
    const int lrow = lane & 15, q = lane >> 4;
    const int r7 = lrow & 7;

    f32x4 acc[4][4] = {};

    // staging slot geometry (identical to round-3, known correct)
    const int s0 = tid;  // slots tid, tid+256, tid+512, tid+768

    auto issue = [&](int kt, int bsel) {
        const int kb16 = (kt & 15) * 64;
        const int ka = kb16 + ((kt >= 32) ? 1024 : 0);             // xh,xh,xl
        const int kb = kb16 + ((kt >= 16 && kt < 32) ? 1024 : 0);  // Wh,Wl,Wh
        const unsigned short* gA = A2 + (size_t)m0 * 2048 + ka;
        const unsigned short* gB = Bt + (size_t)n0 * 2048 + kb;
#pragma unroll
        for (int r = 0; r < 4; ++r) {
            const int s = r * 256 + s0;
            const int row = s >> 3;
            const int gl = (s & 7) ^ (row & 7);  // XOR-swizzled k-group
            __builtin_amdgcn_global_load_lds(GLB(gA + (size_t)row * 2048 + gl * 8),
                                             LDS(&As[bsel][s * 8]), 16, 0, 0);
            __builtin_amdgcn_global_load_lds(GLB(gB + (size_t)row * 2048 + gl * 8),
                                             LDS(&Bs[bsel][s * 8]), 16, 0, 0);
        }
    };

    issue(0, 0);
    __syncthreads();  // tile 0 ready

    for (int kt = 0; kt < 48; ++kt) {
        const int cur = kt & 1;
        if (kt + 1 < 48) issue(kt + 1, cur ^ 1);  // DMA overlaps compute below

#pragma unroll
        for (int kk = 0; kk < 64; kk += 32) {
            const int pg = ((kk >> 3) + q) ^ r7;  // physical (swizzled) group
            bf16x8 a[4], b[4];
#pragma unroll
            for (int mi = 0; mi < 4; ++mi)
                a[mi] = *(const bf16x8*)(&As[cur][(wm + mi * 16 + lrow) * 64 + pg * 8]);
#pragma unroll
            for (int ni = 0; ni < 4; ++ni)
                b[ni] = *(const bf16x8*)(&Bs[cur][(wn + ni * 16 + lrow) * 64 + pg * 8]);
#pragma unroll
            for (int mi = 0; mi < 4; ++mi)
#pragma unroll
                for (int ni = 0; ni < 4; ++ni)
                    acc[mi][ni] = __builtin_amdgcn_mfma_f32_16x16x32_bf16(
                        a[mi], b[ni], acc[mi][ni], 0, 0, 0);
        }
        __syncthreads();  // drains prefetch DMA + protects buffer reuse
    }

    // epilogue: C/D layout col=lane&15, row=q*4+reg
#pragma unroll
    for (int ni = 0; ni < 4; ++ni) {
        const int col = n0 + wn + ni * 16 + lrow;
        const float bv = bias[col];
#pragma unroll
        for (int mi = 0; mi < 4; ++mi)
#pragma unroll
            for (int r = 0; r < 4; ++r) {
                const int row = m0 + wm + mi * 16 + q * 4 + r;
                out[(size_t)row * N + col] = acc[mi][ni][r] + bv;
            }
    }
}

// ---------------------------------------------------------------------------
extern "C" void kernel_launch(void* const* d_in, const int* in_sizes, int n_in,
                              void* d_out, int out_size, void* d_ws, size_t ws_size,
                              hipStream_t stream) {
    const float* x      = (const float*)d_in[0];
    const float* logits = (const float*)d_in[1];
    const float* diags  = (const float*)d_in[2];
    const float* subd   = (const float*)d_in[3];
    const float* supd   = (const float*)d_in[4];
    const float* bias   = (const float*)d_in[5];
    float* out = (float*)d_out;

    const int B = in_sizes[0] / N;  // 4096

    const size_t off_W  = 0;
    const size_t off_Bt = 4u * 1024 * 1024;                 // W:  1024*1024*4 B
    const size_t off_A2 = off_Bt + 4u * 1024 * 1024;        // Bt: 1024*2048*2 B
    const size_t need   = off_A2 + (size_t)B * 2048 * 2;    // A2: B*2048*2 B

    if (ws_size >= need && (B % 128) == 0) {
        float* W           = (float*)((char*)d_ws + off_W);
        unsigned short* Bt = (unsigned short*)((char*)d_ws + off_Bt);
        unsigned short* A2 = (unsigned short*)((char*)d_ws + off_A2);

        build_W<<<dim3(N / 2), dim3(THREADS), 0, stream>>>(logits, diags, subd, supd, W);
        transpose_split<<<dim3(16, 16), dim3(THREADS), 0, stream>>>(W, Bt);
        conv_x<<<dim3(B * N / THREADS), dim3(THREADS), 0, stream>>>(x, A2);
        gemm_split<<<dim3(B / 128, 8), dim3(THREADS), 0, stream>>>(A2, Bt, bias, out);
    } else {
        trifat_kernel<<<dim3(B), dim3(THREADS), 0, stream>>>(
            x, logits, diags, subd, supd, bias, out, B);
    }
}